// Round 12
// baseline (652.010 us; speedup 1.0000x reference)
//
#include <hip/hip_runtime.h>
#include <hip/hip_bf16.h>

#define H 768
#define NB 8
#define SLEN 2048
#define N1 1027
#define N2 517
#define N3 262
#define N4 134

typedef short bf16x8 __attribute__((ext_vector_type(8)));
typedef float f32x4 __attribute__((ext_vector_type(4)));
typedef unsigned short ushortx4 __attribute__((ext_vector_type(4)));
typedef unsigned short ushortx8 __attribute__((ext_vector_type(8)));

__device__ __forceinline__ float sigmoidf(float v) {
    return 1.0f / (1.0f + __expf(-v));
}

__device__ __forceinline__ unsigned short f2bf(float f) {
    union { float f; unsigned u; } v; v.f = f;
    unsigned r = v.u + 0x7fffu + ((v.u >> 16) & 1u);
    return (unsigned short)(r >> 16);
}

__device__ __forceinline__ float bf2f(unsigned short u) {
    union { unsigned u; float f; } v; v.u = ((unsigned)u) << 16;
    return v.f;
}

__device__ __forceinline__ void gload_lds16(const void* g, void* l) {
    __builtin_amdgcn_global_load_lds(
        (const __attribute__((address_space(1))) unsigned int*)g,
        (__attribute__((address_space(3))) unsigned int*)l,
        16, 0, 0);
}

__device__ __forceinline__ float4 ld4(const float* p) { return *(const float4*)p; }
__device__ __forceinline__ float4 ld4(const unsigned short* p) {
    ushortx4 v = *(const ushortx4*)p;
    float4 o; o.x = bf2f(v[0]); o.y = bf2f(v[1]); o.z = bf2f(v[2]); o.w = bf2f(v[3]);
    return o;
}
__device__ __forceinline__ void st4(float* p, float4 v) { *(float4*)p = v; }
__device__ __forceinline__ void st4(unsigned short* p, float4 v) {
    ushortx4 o; o[0] = f2bf(v.x); o[1] = f2bf(v.y); o[2] = f2bf(v.z); o[3] = f2bf(v.w);
    *(ushortx4*)p = o;
}

// ---------------- Forward DWT: rolling-window, 16 t per block, bf16 outputs ----------------
template<typename InT>
__global__ __launch_bounds__(192)
void dwt_analysis_kernel(const InT* __restrict__ in,
                         unsigned short* __restrict__ lo_bf,
                         unsigned short* __restrict__ hi_bf,
                         int n_in, int n_out, int rows_pad,
                         long j_stride, long b_stride, long t_stride)
{
    const float h0r[8] = { 0.2303778133088965f,  0.7148465705529157f,  0.6308807679298589f,
                          -0.027983769416859854f, -0.18703481171909309f, 0.030841381835560764f,
                           0.0328830116668852f, -0.010597401785069032f };
    const float h1r[8] = { -0.010597401785069032f, -0.0328830116668852f, 0.030841381835560764f,
                            0.18703481171909309f, -0.027983769416859854f, -0.6308807679298589f,
                            0.7148465705529157f, -0.2303778133088965f };
    const int tbase = blockIdx.x * 16;
    const int jb = blockIdx.y;
    const int j = jb >> 3, b = jb & 7;
    const int h = threadIdx.x * 4;
    const InT* src = in + j * j_stride + b * b_stride + h;
    const float4 z4 = make_float4(0.f, 0.f, 0.f, 0.f);

    float4 w[8];
#pragma unroll
    for (int k = 0; k < 8; ++k) {
        int s = 2 * tbase - 6 + k;
        w[k] = (s >= 0 && s < n_in) ? ld4(src + (long)s * t_stride) : z4;
    }
#pragma unroll
    for (int tt = 0; tt < 16; ++tt) {
        const int t = tbase + tt;
        if (t < n_out) {
            float lx = 0.f, ly = 0.f, lz = 0.f, lw = 0.f;
            float hx = 0.f, hy = 0.f, hz = 0.f, hw = 0.f;
#pragma unroll
            for (int k = 0; k < 8; ++k) {
                float4 v = w[(2 * tt + k) & 7];
                lx += v.x * h0r[k]; ly += v.y * h0r[k]; lz += v.z * h0r[k]; lw += v.w * h0r[k];
                hx += v.x * h1r[k]; hy += v.y * h1r[k]; hz += v.z * h1r[k]; hw += v.w * h1r[k];
            }
            const long prow = (long)j * rows_pad + b * n_out + t;
            ushortx4 p; p[0] = f2bf(lx); p[1] = f2bf(ly); p[2] = f2bf(lz); p[3] = f2bf(lw);
            *(ushortx4*)(lo_bf + prow * H + h) = p;
            ushortx4 qv; qv[0] = f2bf(hx); qv[1] = f2bf(hy); qv[2] = f2bf(hz); qv[3] = f2bf(hw);
            *(ushortx4*)(hi_bf + prow * H + h) = qv;
        }
        if (tt < 15) {
            int s0n = 2 * t + 2;
            w[(2 * tt) & 7]     = (s0n     < n_in) ? ld4(src + (long)s0n * t_stride)       : z4;
            w[(2 * tt + 1) & 7] = (s0n + 1 < n_in) ? ld4(src + (long)(s0n + 1) * t_stride) : z4;
        }
    }
}

// ---------------- Inverse DWT: rolling-window ----------------
__device__ __forceinline__ void synth_pair(const float4* wl, const float4* wh, int u,
                                           float4* oe, float4* oo)
{
    const float g0[8] = { -0.010597401785069032f, 0.0328830116668852f, 0.030841381835560764f,
                          -0.18703481171909309f, -0.027983769416859854f, 0.6308807679298589f,
                           0.7148465705529157f, 0.2303778133088965f };
    const float g1[8] = { -0.2303778133088965f, 0.7148465705529157f, -0.6308807679298589f,
                          -0.027983769416859854f, 0.18703481171909309f, 0.030841381835560764f,
                          -0.0328830116668852f, -0.010597401785069032f };
    float ex = 0.f, ey = 0.f, ez = 0.f, ew = 0.f;
    float ox = 0.f, oy = 0.f, oz = 0.f, ow = 0.f;
#pragma unroll
    for (int d = 0; d < 4; ++d) {
        float4 vl = wl[(u + d) & 3];
        float4 vh = wh[(u + d) & 3];
        const float cle = g0[2 * d + 1], che = g1[2 * d + 1];
        const float clo = g0[2 * d],     cho = g1[2 * d];
        ex += vl.x * cle + vh.x * che; ey += vl.y * cle + vh.y * che;
        ez += vl.z * cle + vh.z * che; ew += vl.w * cle + vh.w * che;
        ox += vl.x * clo + vh.x * cho; oy += vl.y * clo + vh.y * cho;
        oz += vl.z * clo + vh.z * cho; ow += vl.w * clo + vh.w * cho;
    }
    oe->x = ex; oe->y = ey; oe->z = ez; oe->w = ew;
    oo->x = ox; oo->y = oy; oo->z = oz; oo->w = ow;
}

template<typename LoT, typename HiT, typename OutT>
__global__ __launch_bounds__(192)
void dwt_synth_kernel(const LoT* __restrict__ lo,
                      const HiT* __restrict__ hi,
                      OutT* __restrict__ out,
                      int n, int lo_alloc, int n_out)
{
    const int ubase = blockIdx.x * 16;
    const int mb = blockIdx.y;
    const int h = threadIdx.x * 4;
    const LoT* lop = lo + (long)mb * lo_alloc * H + h;
    const HiT* hip_ = hi + (long)mb * n * H + h;
    OutT* outp = out + (long)mb * n_out * H + h;
    const float4 z4 = make_float4(0.f, 0.f, 0.f, 0.f);

    float4 wl[4], wh[4];
#pragma unroll
    for (int d = 0; d < 4; ++d) {
        int i = ubase + d;
        bool ok = (i < n);
        wl[(ubase + d) & 3] = ok ? ld4(lop + (long)i * H) : z4;
        wh[(ubase + d) & 3] = ok ? ld4(hip_ + (long)i * H) : z4;
    }
#pragma unroll
    for (int uu = 0; uu < 16; ++uu) {
        const int u = ubase + uu;
        if (2 * u < n_out) {
            float4 oe, oo;
            synth_pair(wl, wh, u, &oe, &oo);
            st4(outp + (long)(2 * u) * H, oe);
            st4(outp + (long)(2 * u + 1) * H, oo);
        }
        if (uu < 15) {
            int i = u + 4;
            bool ok = (i < n);
            wl[u & 3] = ok ? ld4(lop + (long)i * H) : z4;
            wh[u & 3] = ok ? ld4(hip_ + (long)i * H) : z4;
        }
    }
}

template<typename LoT, typename HiT>
__global__ __launch_bounds__(192)
void dwt_synth_final_kernel(const LoT* __restrict__ lo,
                            const HiT* __restrict__ hi,
                            const float* __restrict__ x,
                            const float* __restrict__ weight,
                            float* __restrict__ out,
                            int n, int lo_alloc)
{
    const int ubase = blockIdx.x * 16;
    const int mb = blockIdx.y;
    const int m = mb >> 3, b = mb & 7;
    const int h = threadIdx.x * 4;
    const LoT* lop = lo + (long)mb * lo_alloc * H + h;
    const HiT* hip_ = hi + (long)mb * n * H + h;
    const float* xp = x + ((long)b * SLEN) * 2304 + (long)m * H + h;
    float* outp = out + (long)mb * SLEN * H + h;
    const float wgt = weight[m];
    const float4 z4 = make_float4(0.f, 0.f, 0.f, 0.f);

    float4 wl[4], wh[4];
#pragma unroll
    for (int d = 0; d < 4; ++d) {
        int i = ubase + d;
        bool ok = (i < n);
        wl[(ubase + d) & 3] = ok ? ld4(lop + (long)i * H) : z4;
        wh[(ubase + d) & 3] = ok ? ld4(hip_ + (long)i * H) : z4;
    }
#pragma unroll
    for (int uu = 0; uu < 16; ++uu) {
        const int u = ubase + uu;
        {
            float4 oe, oo;
            synth_pair(wl, wh, u, &oe, &oo);
            float4 xe = *(const float4*)(xp + (long)(2 * u) * 2304);
            float4 xo = *(const float4*)(xp + (long)(2 * u + 1) * 2304);
            float4 re, ro;
            re.x = (oe.x - xe.x) * wgt; re.y = (oe.y - xe.y) * wgt;
            re.z = (oe.z - xe.z) * wgt; re.w = (oe.w - xe.w) * wgt;
            ro.x = (oo.x - xo.x) * wgt; ro.y = (oo.y - xo.y) * wgt;
            ro.z = (oo.z - xo.z) * wgt; ro.w = (oo.w - xo.w) * wgt;
            *(float4*)(outp + (long)(2 * u) * H) = re;
            *(float4*)(outp + (long)(2 * u + 1) * H) = ro;
        }
        if (uu < 15) {
            int i = u + 4;
            bool ok = (i < n);
            wl[u & 3] = ok ? ld4(lop + (long)i * H) : z4;
            wh[u & 3] = ok ? ld4(hip_ + (long)i * H) : z4;
        }
    }
}

// ---------------- weight bf16 conversion ----------------
__global__ __launch_bounds__(256)
void cvt_weights_kernel(const float* __restrict__ low_w,
                        const float* __restrict__ high_w,
                        unsigned short* __restrict__ Wl,
                        unsigned short* __restrict__ Wh)
{
    const long HH = (long)H * H;
    const long nlow8 = 9L * HH / 8;
    const long total8 = 45L * HH / 8;
    long stride = (long)gridDim.x * blockDim.x;
    for (long idx = (long)blockIdx.x * blockDim.x + threadIdx.x; idx < total8; idx += stride) {
        const float* src;
        unsigned short* dst;
        if (idx < nlow8) { long e = idx * 8; src = low_w + e; dst = Wl + e; }
        else             { long e = (idx - nlow8) * 8; src = high_w + e; dst = Wh + e; }
        float4 a = *(const float4*)src;
        float4 b = *(const float4*)(src + 4);
        ushortx8 o;
        o[0] = f2bf(a.x); o[1] = f2bf(a.y); o[2] = f2bf(a.z); o[3] = f2bf(a.w);
        o[4] = f2bf(b.x); o[5] = f2bf(b.y); o[6] = f2bf(b.z); o[7] = f2bf(b.w);
        *(ushortx8*)dst = o;
    }
}

// ---------------- Fused gating via MFMA: 4-deep BK=32 ring pipeline ----------------
// 128x128 tile, 8 waves (2 wr x 4 wc), per-wave 64x32. 72 BK=32 substeps (24/j),
// 4x16KB ring buffers (64KB total), prefetch depth 3, counted vmcnt(6) steady state.
// T2 slot swizzle both sides, LDS gate capture (substep gBlk*4+wc), bf16 F output.
#define A1OFF 0L
#define A2OFF 19169280L
#define A3OFF 28901376L
#define A4OFF 33914880L
#define ALOFF 36569088L
#define WLOFF 39223296L
#define WHOFF 44531712L
#define F1OFF 0L
#define F2OFF 18929664L
#define F3OFF 28459008L
#define F4OFF 33288192L
#define FLOFF 35758080L
#define HHL (768L * 768L)

__global__ __launch_bounds__(512, 4)
void gating_mfma_kernel(const unsigned short* __restrict__ R2,
                        float* __restrict__ F0)
{
    __shared__ unsigned short ldsA[4][128 * 32];   // [buf] — 8KB each
    __shared__ unsigned short ldsB[4][128 * 32];
    const int tid = threadIdx.x;
    const int lane = tid & 63;
    const int wid = tid >> 6;          // 0..7
    const int wr = wid >> 2;           // 0..1 : 64-row half
    const int wc = wid & 3;            // 0..3 : 32-col quarter
    const int kq = lane >> 4;          // 0..3
    const int lr = lane & 15;

    // bijective XCD swizzle over nwg = 133*18 = 2394, col-fastest decode
    const int nwg = 2394;
    const int orig = blockIdx.x;
    const int q = nwg >> 3, rm = nwg & 7;
    const int xcd = orig & 7, bidx = orig >> 3;
    const int swz = (xcd < rm) ? (xcd * (q + 1) + bidx)
                               : (rm * (q + 1) + (xcd - rm) * q + bidx);
    const int rt = swz / 18;
    const int ct = swz - rt * 18;
    const int m = ct / 6;
    const int gBlk = ct - m * 6;

    int rtl, rowsReal, rowsPad; long aOff, fOff, wOff, wm;
    if (rt < 65)       { rtl = rt;       rowsReal = 8216; rowsPad = 8320; aOff = A1OFF; fOff = F1OFF; wOff = WHOFF + 0 * 3 * HHL; wm = 12 * HHL; }
    else if (rt < 98)  { rtl = rt - 65;  rowsReal = 4136; rowsPad = 4224; aOff = A2OFF; fOff = F2OFF; wOff = WHOFF + 1 * 3 * HHL; wm = 12 * HHL; }
    else if (rt < 115) { rtl = rt - 98;  rowsReal = 2096; rowsPad = 2176; aOff = A3OFF; fOff = F3OFF; wOff = WHOFF + 2 * 3 * HHL; wm = 12 * HHL; }
    else if (rt < 124) { rtl = rt - 115; rowsReal = 1072; rowsPad = 1152; aOff = A4OFF; fOff = F4OFF; wOff = WHOFF + 3 * 3 * HHL; wm = 12 * HHL; }
    else               { rtl = rt - 124; rowsReal = 1072; rowsPad = 1152; aOff = ALOFF; fOff = FLOFF; wOff = WLOFF;              wm = 3 * HHL; }
    const int rowLocal = rtl * 128;

    // gate substep for this wave: cols [gBlk*128 + wc*32, +32) == substep gBlk*4+wc of each j
    const int ctw = gBlk * 4 + wc;     // 0..23

    // staging: wave wid covers rows [wid*16, wid*16+16); global column PRE-SWIZZLED
    const int srow = wid * 16 + (lane >> 2);                    // 0..127
    const int scol = 8 * ((lane & 3) ^ ((lane >> 3) & 3));      // inverse-swizzled source

    // read-side slot XOR
    const int sl = kq ^ ((lr >> 1) & 3);

    // per-j uniform staging pointers
    const unsigned short* Ag[3];
    const unsigned short* Wg[3];
    const unsigned short* Wb = R2 + wOff + (long)m * wm;
#pragma unroll
    for (int j = 0; j < 3; ++j) {
        Ag[j] = R2 + aOff + (long)j * rowsPad * H + (long)(rowLocal + srow) * H + scol;
        Wg[j] = Wb + (long)j * HHL + (long)(gBlk * 128 + srow) * H + scol;
    }

    f32x4 fus[4][2], acc[4][2];
    unsigned gp[4][2][2];
#pragma unroll
    for (int a = 0; a < 4; ++a)
#pragma unroll
        for (int b = 0; b < 2; ++b) { fus[a][b] = (f32x4)0.f; acc[a][b] = (f32x4)0.f; }

    // STAGE(buf, substep): 2 loads/thread (A, B), substep = j*24 + kt, col = kt*32
#define STAGE(buf, ss) do {                                                     \
    const int jj_ = (ss) / 24;                                                  \
    const int kk_ = ((ss) - jj_ * 24) * 32;                                     \
    gload_lds16(Ag[jj_] + kk_, (char*)&ldsA[buf][0] + wid * 1024);              \
    gload_lds16(Wg[jj_] + kk_, (char*)&ldsB[buf][0] + wid * 1024);              \
} while (0)

    STAGE(0, 0);
    STAGE(1, 1);
    STAGE(2, 2);
    STAGE(3, 3);

#pragma unroll
    for (int t = 0; t < 72; ++t) {
        const int cur = t & 3;                 // compile-time (full unroll)
        const int j = t / 24;
        const int kt = t - j * 24;             // substep 0..23 within j

        // counted wait: steady state 3 STAGEs (6 loads) in flight
        if (t < 69)      asm volatile("s_waitcnt vmcnt(6)" ::: "memory");
        else if (t == 69) asm volatile("s_waitcnt vmcnt(4)" ::: "memory");
        else if (t == 70) asm volatile("s_waitcnt vmcnt(2)" ::: "memory");
        else             asm volatile("s_waitcnt vmcnt(0)" ::: "memory");
        __builtin_amdgcn_s_barrier();          // substep t fully landed (all waves)

        if (kt == ctw) {   // capture gate coeffs from LDS (wave-uniform, once per j)
            const unsigned short* gsrc = &ldsA[cur][0];
#pragma unroll
            for (int mi = 0; mi < 4; ++mi)
#pragma unroll
                for (int ni = 0; ni < 2; ++ni)
#pragma unroll
                    for (int rp = 0; rp < 2; ++rp) {
                        const int rl = wr * 64 + mi * 16 + kq * 4 + rp * 2;
                        const int ec = ni * 16 + lr;                       // col 0..31
                        const int slotg = (ec >> 3) ^ ((kq * 2 + rp) & 3); // (rl>>1)&3
                        const int eoff = slotg * 8 + (ec & 7);
                        unsigned a0 = gsrc[rl * 32 + eoff];
                        unsigned a1 = gsrc[(rl + 1) * 32 + eoff];
                        gp[mi][ni][rp] = a0 | (a1 << 16);
                    }
        }

        {
            bf16x8 af[4], bfr[2];
#pragma unroll
            for (int mi = 0; mi < 4; ++mi)
                af[mi] = *(const bf16x8*)&ldsA[cur][(wr * 64 + mi * 16 + lr) * 32 + sl * 8];
#pragma unroll
            for (int ni = 0; ni < 2; ++ni)
                bfr[ni] = *(const bf16x8*)&ldsB[cur][(wc * 32 + ni * 16 + lr) * 32 + sl * 8];
#pragma unroll
            for (int mi = 0; mi < 4; ++mi)
#pragma unroll
                for (int ni = 0; ni < 2; ++ni)
                    acc[mi][ni] = __builtin_amdgcn_mfma_f32_16x16x32_bf16(
                        af[mi], bfr[ni], acc[mi][ni], 0, 0, 0);
        }

        if (kt == 23) {   // gate epilogue for this j (compile-time)
#pragma unroll
            for (int mi = 0; mi < 4; ++mi)
#pragma unroll
                for (int ni = 0; ni < 2; ++ni) {
#pragma unroll
                    for (int rp = 0; rp < 2; ++rp) {
                        float c0 = bf2f((unsigned short)(gp[mi][ni][rp] & 0xffffu));
                        float c1 = bf2f((unsigned short)(gp[mi][ni][rp] >> 16));
                        fus[mi][ni][rp * 2]     += sigmoidf(acc[mi][ni][rp * 2])     * c0;
                        fus[mi][ni][rp * 2 + 1] += sigmoidf(acc[mi][ni][rp * 2 + 1]) * c1;
                    }
                    acc[mi][ni] = (f32x4)0.f;
                }
        }

        asm volatile("" ::: "memory");         // ds_reads pinned before barrier
        __builtin_amdgcn_s_barrier();          // all waves done reading substep t
        asm volatile("" ::: "memory");         // STAGE pinned after barrier
        if (t < 68) STAGE(cur, t + 4);         // refill just-freed ring slot
    }
#undef STAGE

    unsigned short* Fb = (unsigned short*)(F0 + fOff);
#pragma unroll
    for (int mi = 0; mi < 4; ++mi)
#pragma unroll
        for (int ni = 0; ni < 2; ++ni)
#pragma unroll
            for (int reg = 0; reg < 4; ++reg) {
                const int rl = wr * 64 + mi * 16 + kq * 4 + reg;
                const int r = rowLocal + rl;
                if (r < rowsReal) {
                    const int g = gBlk * 128 + wc * 32 + ni * 16 + lr;
                    Fb[((long)m * rowsReal + r) * H + g] = f2bf(fus[mi][ni][reg]);
                }
            }
}

// ---------------- launch ----------------
static inline int grid_for(long total) {
    long g = (total + 255) / 256;
    if (g > 16384) g = 16384;
    return (int)g;
}

extern "C" void kernel_launch(void* const* d_in, const int* in_sizes, int n_in,
                              void* d_out, int out_size, void* d_ws, size_t ws_size,
                              hipStream_t stream)
{
    const float* x      = (const float*)d_in[0];
    const float* low_w  = (const float*)d_in[1];
    const float* high_w = (const float*)d_in[2];
    const float* weight = (const float*)d_in[3];
    float* out = (float*)d_out;
    float* ws  = (float*)d_ws;

    const long HH = (long)H * H;
    const int rows1p = 8320, rows2p = 4224, rows3p = 2176, rows4p = 1152;

    // Region 1: bf16 lo intermediates during forward; bf16 fused planes after
    unsigned short* Blo1 = (unsigned short*)ws;
    unsigned short* Blo2 = Blo1 + 3L * rows1p * H;
    unsigned short* Blo3 = Blo2 + 3L * rows2p * H;
    unsigned short* F_hi1b = (unsigned short*)(ws + F1OFF);
    unsigned short* F_hi2b = (unsigned short*)(ws + F2OFF);
    unsigned short* F_hi3b = (unsigned short*)(ws + F3OFF);
    unsigned short* F_hi4b = (unsigned short*)(ws + F4OFF);
    unsigned short* F_lob  = (unsigned short*)(ws + FLOFF);

    // Region 2: bf16 coeffs + weights; bf16 synthesis Y after
    const long SZF = 24L * (N1 + N2 + N3 + 2 * N4) * H;
    float* R2f = ws + SZF;
    unsigned short* R2 = (unsigned short*)R2f;
    unsigned short* Abf1 = R2 + A1OFF;
    unsigned short* Abf2 = R2 + A2OFF;
    unsigned short* Abf3 = R2 + A3OFF;
    unsigned short* Abf4 = R2 + A4OFF;
    unsigned short* AbfL = R2 + ALOFF;
    unsigned short* Wl   = R2 + WLOFF;
    unsigned short* Wh   = R2 + WHOFF;
    unsigned short* Y1 = R2;                     // aliases dead bf16 coeff region
    unsigned short* Y2 = Y1 + 24L * 262 * H;
    unsigned short* Y3 = Y2 + 24L * 518 * H;

    // ---- forward DWT (rolling window, bf16 lo chain) ----
    hipLaunchKernelGGL((dwt_analysis_kernel<float>), dim3((N1 + 15) / 16, 24), dim3(192), 0, stream,
                       x, Blo1, Abf1,
                       SLEN, N1, rows1p, 768L, (long)SLEN * 2304, 2304L);
    hipLaunchKernelGGL((dwt_analysis_kernel<unsigned short>), dim3((N2 + 15) / 16, 24), dim3(192), 0, stream,
                       Blo1, Blo2, Abf2,
                       N1, N2, rows2p, (long)rows1p * H, (long)N1 * H, (long)H);
    hipLaunchKernelGGL((dwt_analysis_kernel<unsigned short>), dim3((N3 + 15) / 16, 24), dim3(192), 0, stream,
                       Blo2, Blo3, Abf3,
                       N2, N3, rows3p, (long)rows2p * H, (long)N2 * H, (long)H);
    hipLaunchKernelGGL((dwt_analysis_kernel<unsigned short>), dim3((N4 + 15) / 16, 24), dim3(192), 0, stream,
                       Blo3, AbfL, Abf4,
                       N3, N4, rows4p, (long)rows3p * H, (long)N3 * H, (long)H);

    // ---- weight conversion ----
    hipLaunchKernelGGL(cvt_weights_kernel, dim3(grid_for(45L * HH / 8)), dim3(256), 0, stream,
                       low_w, high_w, Wl, Wh);

    // ---- gating (MFMA, one dispatch, 4-deep ring pipeline; all bands -> bf16 F) ----
    hipLaunchKernelGGL(gating_mfma_kernel, dim3(2394), dim3(512), 0, stream, R2, ws);

    // ---- inverse DWT (rolling window, all-bf16 planes; Y aliases dead coeff region) ----
    hipLaunchKernelGGL((dwt_synth_kernel<unsigned short, unsigned short, unsigned short>),
                       dim3(9, 24), dim3(192), 0, stream,
                       F_lob, F_hi4b, Y1, N4, N4, 262);
    hipLaunchKernelGGL((dwt_synth_kernel<unsigned short, unsigned short, unsigned short>),
                       dim3(17, 24), dim3(192), 0, stream,
                       Y1, F_hi3b, Y2, N3, 262, 518);
    hipLaunchKernelGGL((dwt_synth_kernel<unsigned short, unsigned short, unsigned short>),
                       dim3(33, 24), dim3(192), 0, stream,
                       Y2, F_hi2b, Y3, N2, 518, 1028);
    hipLaunchKernelGGL((dwt_synth_final_kernel<unsigned short, unsigned short>),
                       dim3(64, 24), dim3(192), 0, stream,
                       Y3, F_hi1b, x, weight, out, N1, 1028);
}

// Round 13
// 553.080 us; speedup vs baseline: 1.1789x; 1.1789x over previous
//
#include <hip/hip_runtime.h>
#include <hip/hip_bf16.h>

#define H 768
#define NB 8
#define SLEN 2048
#define N1 1027
#define N2 517
#define N3 262
#define N4 134

typedef short bf16x8 __attribute__((ext_vector_type(8)));
typedef float f32x4 __attribute__((ext_vector_type(4)));
typedef unsigned short ushortx4 __attribute__((ext_vector_type(4)));
typedef unsigned short ushortx8 __attribute__((ext_vector_type(8)));

__device__ __forceinline__ float sigmoidf(float v) {
    return 1.0f / (1.0f + __expf(-v));
}

__device__ __forceinline__ unsigned short f2bf(float f) {
    union { float f; unsigned u; } v; v.f = f;
    unsigned r = v.u + 0x7fffu + ((v.u >> 16) & 1u);
    return (unsigned short)(r >> 16);
}

__device__ __forceinline__ float bf2f(unsigned short u) {
    union { unsigned u; float f; } v; v.u = ((unsigned)u) << 16;
    return v.f;
}

__device__ __forceinline__ void gload_lds16(const void* g, void* l) {
    __builtin_amdgcn_global_load_lds(
        (const __attribute__((address_space(1))) unsigned int*)g,
        (__attribute__((address_space(3))) unsigned int*)l,
        16, 0, 0);
}

__device__ __forceinline__ float4 ld4(const float* p) { return *(const float4*)p; }
__device__ __forceinline__ float4 ld4(const unsigned short* p) {
    ushortx4 v = *(const ushortx4*)p;
    float4 o; o.x = bf2f(v[0]); o.y = bf2f(v[1]); o.z = bf2f(v[2]); o.w = bf2f(v[3]);
    return o;
}
__device__ __forceinline__ void st4(float* p, float4 v) { *(float4*)p = v; }
__device__ __forceinline__ void st4(unsigned short* p, float4 v) {
    ushortx4 o; o[0] = f2bf(v.x); o[1] = f2bf(v.y); o[2] = f2bf(v.z); o[3] = f2bf(v.w);
    *(ushortx4*)p = o;
}

// ---------------- Forward DWT: rolling-window, 16 t per block, bf16 outputs ----------------
template<typename InT>
__global__ __launch_bounds__(192)
void dwt_analysis_kernel(const InT* __restrict__ in,
                         unsigned short* __restrict__ lo_bf,
                         unsigned short* __restrict__ hi_bf,
                         int n_in, int n_out, int rows_pad,
                         long j_stride, long b_stride, long t_stride)
{
    const float h0r[8] = { 0.2303778133088965f,  0.7148465705529157f,  0.6308807679298589f,
                          -0.027983769416859854f, -0.18703481171909309f, 0.030841381835560764f,
                           0.0328830116668852f, -0.010597401785069032f };
    const float h1r[8] = { -0.010597401785069032f, -0.0328830116668852f, 0.030841381835560764f,
                            0.18703481171909309f, -0.027983769416859854f, -0.6308807679298589f,
                            0.7148465705529157f, -0.2303778133088965f };
    const int tbase = blockIdx.x * 16;
    const int jb = blockIdx.y;
    const int j = jb >> 3, b = jb & 7;
    const int h = threadIdx.x * 4;
    const InT* src = in + j * j_stride + b * b_stride + h;
    const float4 z4 = make_float4(0.f, 0.f, 0.f, 0.f);

    float4 w[8];
#pragma unroll
    for (int k = 0; k < 8; ++k) {
        int s = 2 * tbase - 6 + k;
        w[k] = (s >= 0 && s < n_in) ? ld4(src + (long)s * t_stride) : z4;
    }
#pragma unroll
    for (int tt = 0; tt < 16; ++tt) {
        const int t = tbase + tt;
        if (t < n_out) {
            float lx = 0.f, ly = 0.f, lz = 0.f, lw = 0.f;
            float hx = 0.f, hy = 0.f, hz = 0.f, hw = 0.f;
#pragma unroll
            for (int k = 0; k < 8; ++k) {
                float4 v = w[(2 * tt + k) & 7];
                lx += v.x * h0r[k]; ly += v.y * h0r[k]; lz += v.z * h0r[k]; lw += v.w * h0r[k];
                hx += v.x * h1r[k]; hy += v.y * h1r[k]; hz += v.z * h1r[k]; hw += v.w * h1r[k];
            }
            const long prow = (long)j * rows_pad + b * n_out + t;
            ushortx4 p; p[0] = f2bf(lx); p[1] = f2bf(ly); p[2] = f2bf(lz); p[3] = f2bf(lw);
            *(ushortx4*)(lo_bf + prow * H + h) = p;
            ushortx4 qv; qv[0] = f2bf(hx); qv[1] = f2bf(hy); qv[2] = f2bf(hz); qv[3] = f2bf(hw);
            *(ushortx4*)(hi_bf + prow * H + h) = qv;
        }
        if (tt < 15) {
            int s0n = 2 * t + 2;
            w[(2 * tt) & 7]     = (s0n     < n_in) ? ld4(src + (long)s0n * t_stride)       : z4;
            w[(2 * tt + 1) & 7] = (s0n + 1 < n_in) ? ld4(src + (long)(s0n + 1) * t_stride) : z4;
        }
    }
}

// ---------------- Inverse DWT: rolling-window ----------------
__device__ __forceinline__ void synth_pair(const float4* wl, const float4* wh, int u,
                                           float4* oe, float4* oo)
{
    const float g0[8] = { -0.010597401785069032f, 0.0328830116668852f, 0.030841381835560764f,
                          -0.18703481171909309f, -0.027983769416859854f, 0.6308807679298589f,
                           0.7148465705529157f, 0.2303778133088965f };
    const float g1[8] = { -0.2303778133088965f, 0.7148465705529157f, -0.6308807679298589f,
                          -0.027983769416859854f, 0.18703481171909309f, 0.030841381835560764f,
                          -0.0328830116668852f, -0.010597401785069032f };
    float ex = 0.f, ey = 0.f, ez = 0.f, ew = 0.f;
    float ox = 0.f, oy = 0.f, oz = 0.f, ow = 0.f;
#pragma unroll
    for (int d = 0; d < 4; ++d) {
        float4 vl = wl[(u + d) & 3];
        float4 vh = wh[(u + d) & 3];
        const float cle = g0[2 * d + 1], che = g1[2 * d + 1];
        const float clo = g0[2 * d],     cho = g1[2 * d];
        ex += vl.x * cle + vh.x * che; ey += vl.y * cle + vh.y * che;
        ez += vl.z * cle + vh.z * che; ew += vl.w * cle + vh.w * che;
        ox += vl.x * clo + vh.x * cho; oy += vl.y * clo + vh.y * cho;
        oz += vl.z * clo + vh.z * cho; ow += vl.w * clo + vh.w * cho;
    }
    oe->x = ex; oe->y = ey; oe->z = ez; oe->w = ew;
    oo->x = ox; oo->y = oy; oo->z = oz; oo->w = ow;
}

template<typename LoT, typename HiT, typename OutT>
__global__ __launch_bounds__(192)
void dwt_synth_kernel(const LoT* __restrict__ lo,
                      const HiT* __restrict__ hi,
                      OutT* __restrict__ out,
                      int n, int lo_alloc, int n_out)
{
    const int ubase = blockIdx.x * 16;
    const int mb = blockIdx.y;
    const int h = threadIdx.x * 4;
    const LoT* lop = lo + (long)mb * lo_alloc * H + h;
    const HiT* hip_ = hi + (long)mb * n * H + h;
    OutT* outp = out + (long)mb * n_out * H + h;
    const float4 z4 = make_float4(0.f, 0.f, 0.f, 0.f);

    float4 wl[4], wh[4];
#pragma unroll
    for (int d = 0; d < 4; ++d) {
        int i = ubase + d;
        bool ok = (i < n);
        wl[(ubase + d) & 3] = ok ? ld4(lop + (long)i * H) : z4;
        wh[(ubase + d) & 3] = ok ? ld4(hip_ + (long)i * H) : z4;
    }
#pragma unroll
    for (int uu = 0; uu < 16; ++uu) {
        const int u = ubase + uu;
        if (2 * u < n_out) {
            float4 oe, oo;
            synth_pair(wl, wh, u, &oe, &oo);
            st4(outp + (long)(2 * u) * H, oe);
            st4(outp + (long)(2 * u + 1) * H, oo);
        }
        if (uu < 15) {
            int i = u + 4;
            bool ok = (i < n);
            wl[u & 3] = ok ? ld4(lop + (long)i * H) : z4;
            wh[u & 3] = ok ? ld4(hip_ + (long)i * H) : z4;
        }
    }
}

template<typename LoT, typename HiT>
__global__ __launch_bounds__(192)
void dwt_synth_final_kernel(const LoT* __restrict__ lo,
                            const HiT* __restrict__ hi,
                            const float* __restrict__ x,
                            const float* __restrict__ weight,
                            float* __restrict__ out,
                            int n, int lo_alloc)
{
    const int ubase = blockIdx.x * 16;
    const int mb = blockIdx.y;
    const int m = mb >> 3, b = mb & 7;
    const int h = threadIdx.x * 4;
    const LoT* lop = lo + (long)mb * lo_alloc * H + h;
    const HiT* hip_ = hi + (long)mb * n * H + h;
    const float* xp = x + ((long)b * SLEN) * 2304 + (long)m * H + h;
    float* outp = out + (long)mb * SLEN * H + h;
    const float wgt = weight[m];
    const float4 z4 = make_float4(0.f, 0.f, 0.f, 0.f);

    float4 wl[4], wh[4];
#pragma unroll
    for (int d = 0; d < 4; ++d) {
        int i = ubase + d;
        bool ok = (i < n);
        wl[(ubase + d) & 3] = ok ? ld4(lop + (long)i * H) : z4;
        wh[(ubase + d) & 3] = ok ? ld4(hip_ + (long)i * H) : z4;
    }
#pragma unroll
    for (int uu = 0; uu < 16; ++uu) {
        const int u = ubase + uu;
        {
            float4 oe, oo;
            synth_pair(wl, wh, u, &oe, &oo);
            float4 xe = *(const float4*)(xp + (long)(2 * u) * 2304);
            float4 xo = *(const float4*)(xp + (long)(2 * u + 1) * 2304);
            float4 re, ro;
            re.x = (oe.x - xe.x) * wgt; re.y = (oe.y - xe.y) * wgt;
            re.z = (oe.z - xe.z) * wgt; re.w = (oe.w - xe.w) * wgt;
            ro.x = (oo.x - xo.x) * wgt; ro.y = (oo.y - xo.y) * wgt;
            ro.z = (oo.z - xo.z) * wgt; ro.w = (oo.w - xo.w) * wgt;
            *(float4*)(outp + (long)(2 * u) * H) = re;
            *(float4*)(outp + (long)(2 * u + 1) * H) = ro;
        }
        if (uu < 15) {
            int i = u + 4;
            bool ok = (i < n);
            wl[u & 3] = ok ? ld4(lop + (long)i * H) : z4;
            wh[u & 3] = ok ? ld4(hip_ + (long)i * H) : z4;
        }
    }
}

// ---------------- weight bf16 conversion ----------------
__global__ __launch_bounds__(256)
void cvt_weights_kernel(const float* __restrict__ low_w,
                        const float* __restrict__ high_w,
                        unsigned short* __restrict__ Wl,
                        unsigned short* __restrict__ Wh)
{
    const long HH = (long)H * H;
    const long nlow8 = 9L * HH / 8;
    const long total8 = 45L * HH / 8;
    long stride = (long)gridDim.x * blockDim.x;
    for (long idx = (long)blockIdx.x * blockDim.x + threadIdx.x; idx < total8; idx += stride) {
        const float* src;
        unsigned short* dst;
        if (idx < nlow8) { long e = idx * 8; src = low_w + e; dst = Wl + e; }
        else             { long e = (idx - nlow8) * 8; src = high_w + e; dst = Wh + e; }
        float4 a = *(const float4*)src;
        float4 b = *(const float4*)(src + 4);
        ushortx8 o;
        o[0] = f2bf(a.x); o[1] = f2bf(a.y); o[2] = f2bf(a.z); o[3] = f2bf(a.w);
        o[4] = f2bf(b.x); o[5] = f2bf(b.y); o[6] = f2bf(b.z); o[7] = f2bf(b.w);
        *(ushortx8*)dst = o;
    }
}

// ---------------- Fused gating via MFMA (round-7/11 proven structure) ----------------
// 128x128 tile, 8 waves (2 wr x 4 wc), per-wave 64x32, BK=64 (two [128][32] subtiles),
// 2-deep double buffer, counted vmcnt(4), T2 slot swizzle both sides, LDS gate capture.
// ALL bands write fused output as bf16.
#define A1OFF 0L
#define A2OFF 19169280L
#define A3OFF 28901376L
#define A4OFF 33914880L
#define ALOFF 36569088L
#define WLOFF 39223296L
#define WHOFF 44531712L
#define F1OFF 0L
#define F2OFF 18929664L
#define F3OFF 28459008L
#define F4OFF 33288192L
#define FLOFF 35758080L
#define HHL (768L * 768L)

__global__ __launch_bounds__(512, 4)
void gating_mfma_kernel(const unsigned short* __restrict__ R2,
                        float* __restrict__ F0)
{
    __shared__ unsigned short ldsA[2][2][128 * 32];   // [buf][kh]
    __shared__ unsigned short ldsB[2][2][128 * 32];
    const int tid = threadIdx.x;
    const int lane = tid & 63;
    const int wid = tid >> 6;          // 0..7
    const int wr = wid >> 2;           // 0..1 : 64-row half
    const int wc = wid & 3;            // 0..3 : 32-col quarter
    const int kq = lane >> 4;          // 0..3
    const int lr = lane & 15;

    // bijective XCD swizzle over nwg = 133*18 = 2394, col-fastest decode
    const int nwg = 2394;
    const int orig = blockIdx.x;
    const int q = nwg >> 3, rm = nwg & 7;
    const int xcd = orig & 7, bidx = orig >> 3;
    const int swz = (xcd < rm) ? (xcd * (q + 1) + bidx)
                               : (rm * (q + 1) + (xcd - rm) * q + bidx);
    const int rt = swz / 18;
    const int ct = swz - rt * 18;
    const int m = ct / 6;
    const int gBlk = ct - m * 6;

    int rtl, rowsReal, rowsPad; long aOff, fOff, wOff, wm;
    if (rt < 65)       { rtl = rt;       rowsReal = 8216; rowsPad = 8320; aOff = A1OFF; fOff = F1OFF; wOff = WHOFF + 0 * 3 * HHL; wm = 12 * HHL; }
    else if (rt < 98)  { rtl = rt - 65;  rowsReal = 4136; rowsPad = 4224; aOff = A2OFF; fOff = F2OFF; wOff = WHOFF + 1 * 3 * HHL; wm = 12 * HHL; }
    else if (rt < 115) { rtl = rt - 98;  rowsReal = 2096; rowsPad = 2176; aOff = A3OFF; fOff = F3OFF; wOff = WHOFF + 2 * 3 * HHL; wm = 12 * HHL; }
    else if (rt < 124) { rtl = rt - 115; rowsReal = 1072; rowsPad = 1152; aOff = A4OFF; fOff = F4OFF; wOff = WHOFF + 3 * 3 * HHL; wm = 12 * HHL; }
    else               { rtl = rt - 124; rowsReal = 1072; rowsPad = 1152; aOff = ALOFF; fOff = FLOFF; wOff = WLOFF;              wm = 3 * HHL; }
    const int rowLocal = rtl * 128;

    // gate column block for this wave (wave-uniform)
    const int gcol = gBlk * 128 + wc * 32;
    const int k0_g = gcol & ~63;
    const int kh_g = wc & 1;

    // staging: wave wid covers rows [wid*16, wid*16+16); global column PRE-SWIZZLED
    const int srow = wid * 16 + (lane >> 2);                    // 0..127
    const int scol = 8 * ((lane & 3) ^ ((lane >> 3) & 3));      // inverse-swizzled source

    // read-side slot XOR
    const int sl = kq ^ ((lr >> 1) & 3);

    // per-j uniform staging pointers
    const unsigned short* Ag[3];
    const unsigned short* Wg[3];
    const unsigned short* Wb = R2 + wOff + (long)m * wm;
#pragma unroll
    for (int j = 0; j < 3; ++j) {
        Ag[j] = R2 + aOff + (long)j * rowsPad * H + (long)(rowLocal + srow) * H + scol;
        Wg[j] = Wb + (long)j * HHL + (long)(gBlk * 128 + srow) * H + scol;
    }

    f32x4 fus[4][2], acc[4][2];
    unsigned gp[4][2][2];
#pragma unroll
    for (int a = 0; a < 4; ++a)
#pragma unroll
        for (int b = 0; b < 2; ++b) { fus[a][b] = (f32x4)0.f; acc[a][b] = (f32x4)0.f; }

#define STAGE(buf, jj, kk) do {                                              \
    gload_lds16(Ag[jj] + (kk),      (char*)&ldsA[buf][0][0] + wid * 1024);   \
    gload_lds16(Ag[jj] + (kk) + 32, (char*)&ldsA[buf][1][0] + wid * 1024);   \
    gload_lds16(Wg[jj] + (kk),      (char*)&ldsB[buf][0][0] + wid * 1024);   \
    gload_lds16(Wg[jj] + (kk) + 32, (char*)&ldsB[buf][1][0] + wid * 1024);   \
} while (0)

    STAGE(0, 0, 0);
    STAGE(1, 0, 64);

#pragma unroll
    for (int t = 0; t < 36; ++t) {
        const int cur = t & 1;                 // compile-time (full unroll)
        const int j = t / 12;
        const int kk0 = (t - j * 12) * 64;

        if (t < 35) asm volatile("s_waitcnt vmcnt(4)" ::: "memory");
        else        asm volatile("s_waitcnt vmcnt(0)" ::: "memory");
        __builtin_amdgcn_s_barrier();          // tile t fully landed (all waves)

        if (kk0 == k0_g) {   // capture gate coeffs from LDS (runtime-uniform, once per j)
            const unsigned short* gsrc = kh_g ? &ldsA[cur][1][0] : &ldsA[cur][0][0];
#pragma unroll
            for (int mi = 0; mi < 4; ++mi)
#pragma unroll
                for (int ni = 0; ni < 2; ++ni)
#pragma unroll
                    for (int rp = 0; rp < 2; ++rp) {
                        const int rl = wr * 64 + mi * 16 + kq * 4 + rp * 2;
                        const int ec = ni * 16 + lr;                       // col 0..31
                        const int slotg = (ec >> 3) ^ ((kq * 2 + rp) & 3); // (rl>>1)&3
                        const int eoff = slotg * 8 + (ec & 7);
                        unsigned a0 = gsrc[rl * 32 + eoff];
                        unsigned a1 = gsrc[(rl + 1) * 32 + eoff];
                        gp[mi][ni][rp] = a0 | (a1 << 16);
                    }
        }

#pragma unroll
        for (int kh = 0; kh < 2; ++kh) {
            bf16x8 af[4], bfr[2];
#pragma unroll
            for (int mi = 0; mi < 4; ++mi)
                af[mi] = *(const bf16x8*)&ldsA[cur][kh][(wr * 64 + mi * 16 + lr) * 32 + sl * 8];
#pragma unroll
            for (int ni = 0; ni < 2; ++ni)
                bfr[ni] = *(const bf16x8*)&ldsB[cur][kh][(wc * 32 + ni * 16 + lr) * 32 + sl * 8];
#pragma unroll
            for (int mi = 0; mi < 4; ++mi)
#pragma unroll
                for (int ni = 0; ni < 2; ++ni)
                    acc[mi][ni] = __builtin_amdgcn_mfma_f32_16x16x32_bf16(
                        af[mi], bfr[ni], acc[mi][ni], 0, 0, 0);
        }

        if (t - j * 12 == 11) {   // gate epilogue for this j (compile-time)
#pragma unroll
            for (int mi = 0; mi < 4; ++mi)
#pragma unroll
                for (int ni = 0; ni < 2; ++ni) {
#pragma unroll
                    for (int rp = 0; rp < 2; ++rp) {
                        float c0 = bf2f((unsigned short)(gp[mi][ni][rp] & 0xffffu));
                        float c1 = bf2f((unsigned short)(gp[mi][ni][rp] >> 16));
                        fus[mi][ni][rp * 2]     += sigmoidf(acc[mi][ni][rp * 2])     * c0;
                        fus[mi][ni][rp * 2 + 1] += sigmoidf(acc[mi][ni][rp * 2 + 1]) * c1;
                    }
                    acc[mi][ni] = (f32x4)0.f;
                }
        }

        asm volatile("" ::: "memory");         // ds_reads pinned before barrier
        __builtin_amdgcn_s_barrier();          // all waves done reading tile t
        asm volatile("" ::: "memory");         // STAGE pinned after barrier
        if (t < 34) {
            const int tp = t + 2;
            const int jp = tp / 12;
            STAGE(cur, jp, (tp - jp * 12) * 64);   // refill just-freed buffer
        }
    }
#undef STAGE

    unsigned short* Fb = (unsigned short*)(F0 + fOff);
#pragma unroll
    for (int mi = 0; mi < 4; ++mi)
#pragma unroll
        for (int ni = 0; ni < 2; ++ni)
#pragma unroll
            for (int reg = 0; reg < 4; ++reg) {
                const int rl = wr * 64 + mi * 16 + kq * 4 + reg;
                const int r = rowLocal + rl;
                if (r < rowsReal) {
                    const int g = gBlk * 128 + wc * 32 + ni * 16 + lr;
                    Fb[((long)m * rowsReal + r) * H + g] = f2bf(fus[mi][ni][reg]);
                }
            }
}

// ---------------- launch ----------------
static inline int grid_for(long total) {
    long g = (total + 255) / 256;
    if (g > 16384) g = 16384;
    return (int)g;
}

extern "C" void kernel_launch(void* const* d_in, const int* in_sizes, int n_in,
                              void* d_out, int out_size, void* d_ws, size_t ws_size,
                              hipStream_t stream)
{
    const float* x      = (const float*)d_in[0];
    const float* low_w  = (const float*)d_in[1];
    const float* high_w = (const float*)d_in[2];
    const float* weight = (const float*)d_in[3];
    float* out = (float*)d_out;
    float* ws  = (float*)d_ws;

    const long HH = (long)H * H;
    const int rows1p = 8320, rows2p = 4224, rows3p = 2176, rows4p = 1152;

    // Region 1: bf16 lo intermediates during forward; bf16 fused planes after
    unsigned short* Blo1 = (unsigned short*)ws;
    unsigned short* Blo2 = Blo1 + 3L * rows1p * H;
    unsigned short* Blo3 = Blo2 + 3L * rows2p * H;
    unsigned short* F_hi1b = (unsigned short*)(ws + F1OFF);
    unsigned short* F_hi2b = (unsigned short*)(ws + F2OFF);
    unsigned short* F_hi3b = (unsigned short*)(ws + F3OFF);
    unsigned short* F_hi4b = (unsigned short*)(ws + F4OFF);
    unsigned short* F_lob  = (unsigned short*)(ws + FLOFF);

    // Region 2: bf16 coeffs + weights; bf16 synthesis Y after
    const long SZF = 24L * (N1 + N2 + N3 + 2 * N4) * H;
    float* R2f = ws + SZF;
    unsigned short* R2 = (unsigned short*)R2f;
    unsigned short* Abf1 = R2 + A1OFF;
    unsigned short* Abf2 = R2 + A2OFF;
    unsigned short* Abf3 = R2 + A3OFF;
    unsigned short* Abf4 = R2 + A4OFF;
    unsigned short* AbfL = R2 + ALOFF;
    unsigned short* Wl   = R2 + WLOFF;
    unsigned short* Wh   = R2 + WHOFF;
    unsigned short* Y1 = R2;                     // aliases dead bf16 coeff region
    unsigned short* Y2 = Y1 + 24L * 262 * H;
    unsigned short* Y3 = Y2 + 24L * 518 * H;

    // ---- forward DWT (rolling window, bf16 lo chain) ----
    hipLaunchKernelGGL((dwt_analysis_kernel<float>), dim3((N1 + 15) / 16, 24), dim3(192), 0, stream,
                       x, Blo1, Abf1,
                       SLEN, N1, rows1p, 768L, (long)SLEN * 2304, 2304L);
    hipLaunchKernelGGL((dwt_analysis_kernel<unsigned short>), dim3((N2 + 15) / 16, 24), dim3(192), 0, stream,
                       Blo1, Blo2, Abf2,
                       N1, N2, rows2p, (long)rows1p * H, (long)N1 * H, (long)H);
    hipLaunchKernelGGL((dwt_analysis_kernel<unsigned short>), dim3((N3 + 15) / 16, 24), dim3(192), 0, stream,
                       Blo2, Blo3, Abf3,
                       N2, N3, rows3p, (long)rows2p * H, (long)N2 * H, (long)H);
    hipLaunchKernelGGL((dwt_analysis_kernel<unsigned short>), dim3((N4 + 15) / 16, 24), dim3(192), 0, stream,
                       Blo3, AbfL, Abf4,
                       N3, N4, rows4p, (long)rows3p * H, (long)N3 * H, (long)H);

    // ---- weight conversion ----
    hipLaunchKernelGGL(cvt_weights_kernel, dim3(grid_for(45L * HH / 8)), dim3(256), 0, stream,
                       low_w, high_w, Wl, Wh);

    // ---- gating (MFMA, one dispatch, round-11 structure; all bands -> bf16 F) ----
    hipLaunchKernelGGL(gating_mfma_kernel, dim3(2394), dim3(512), 0, stream, R2, ws);

    // ---- inverse DWT (rolling window, all-bf16 planes; Y aliases dead coeff region) ----
    hipLaunchKernelGGL((dwt_synth_kernel<unsigned short, unsigned short, unsigned short>),
                       dim3(9, 24), dim3(192), 0, stream,
                       F_lob, F_hi4b, Y1, N4, N4, 262);
    hipLaunchKernelGGL((dwt_synth_kernel<unsigned short, unsigned short, unsigned short>),
                       dim3(17, 24), dim3(192), 0, stream,
                       Y1, F_hi3b, Y2, N3, 262, 518);
    hipLaunchKernelGGL((dwt_synth_kernel<unsigned short, unsigned short, unsigned short>),
                       dim3(33, 24), dim3(192), 0, stream,
                       Y2, F_hi2b, Y3, N2, 518, 1028);
    hipLaunchKernelGGL((dwt_synth_final_kernel<unsigned short, unsigned short>),
                       dim3(64, 24), dim3(192), 0, stream,
                       Y3, F_hi1b, x, weight, out, N1, 1028);
}